// Round 16
// baseline (371.603 us; speedup 1.0000x reference)
//
#include <hip/hip_runtime.h>

// Chamfer distance — exact, per-pred pruned scan over x-sorted targets.
//
// History: brute floor 46.3us (R11). Slab/window pruning (R14-R19, all
// absmax 0) never beat brute: per-slab max-aggregation keeps windows
// 10-30x wider than the per-pred optimum (typical NN ~0.07 -> ~180
// targets; slab windows ~2500), and staging/serial overheads ate the
// rest. R20: drop slabs. Each pred two-pointer-walks the sorted target
// array outward from its own x-position; a side stops when
// (dx_next)^2 >= (best+|p|^2)*1.0005 — next-x bounds all remaining on
// that side (x-sorted), so the scanned set provably contains the NN:
// exact (same slack pattern as R15-R19). 4 lanes/pred ({0,1} left
// stride-2, {2,3} right), best exchanged via 2 shfl_xor per 8-chunk;
// per-lane stop uses its OWN next-x (bounds its own subsequence).
// No LDS, no staging, no atomics, no bound pass. ~25M pairs (5% of
// brute). Predict: scan 5-12us, bench 33-48us, absmax 0.
//
// Carried: pk_fma = 2x scalar cost; launch_bounds arg2 = min BLOCKS/CU
// (VGPR cap = 2048/(arg2 x waves)) — scan uses no arg2.

#define NBINS 256
#define XLO -6.0f
#define XHI 6.0f
#define CH 8       // targets per lane per chunk
#define MAXIT 600  // worst lane = M/2 reads / CH = 512; never binding

// bin sort
#define BST 1024

// brute-force fallback params (R11, unchanged)
#define THREADS 512
#define P 8
#define G 128
#define TILE 32
#define LSTRIDE (TILE + 1)
#define TSPLIT 2
#define BUFSZ (32 * LSTRIDE)

typedef float float2_t __attribute__((ext_vector_type(2)));
typedef float float4_t __attribute__((ext_vector_type(4)));

// ---------- pass 1: counting sort by x-bin, emit float4 {x,y,z,|q|^2} ----
__global__ __launch_bounds__(BST) void bin_sort_kernel(
    const float* __restrict__ pred, const float* __restrict__ target,
    float4_t* __restrict__ sorted, int* __restrict__ binBase, int M) {
  int bs = blockIdx.x;  // b*2 + side
  int b = bs >> 1, side = bs & 1;
  const float* src = (side ? target : pred) + (size_t)b * M * 3;
  float4_t* out = sorted + (size_t)bs * M;
  int* bases = binBase + bs * (NBINS + 1);

  __shared__ int cnt[NBINS];
  __shared__ int scan[NBINS];
  __shared__ int cur[NBINS];
  int t = threadIdx.x;
  for (int i = t; i < NBINS; i += BST) cnt[i] = 0;
  __syncthreads();
  const float invW = (float)NBINS / (XHI - XLO);
  for (int i = t; i < M; i += BST) {
    float x = src[i * 3];
    int bin = (int)((x - XLO) * invW);
    bin = bin < 0 ? 0 : (bin > NBINS - 1 ? NBINS - 1 : bin);
    atomicAdd(&cnt[bin], 1);
  }
  __syncthreads();
  if (t < NBINS) scan[t] = cnt[t];
  __syncthreads();
  for (int off = 1; off < NBINS; off <<= 1) {
    int v = 0;
    if (t < NBINS && t >= off) v = scan[t - off];
    __syncthreads();
    if (t < NBINS) scan[t] += v;
    __syncthreads();
  }
  if (t < NBINS) {
    int excl = scan[t] - cnt[t];
    bases[t] = excl;
    cur[t] = excl;
  }
  if (t == 0) bases[NBINS] = M;
  __syncthreads();
  for (int i = t; i < M; i += BST) {
    float x = src[i * 3], y = src[i * 3 + 1], z = src[i * 3 + 2];
    int bin = (int)((x - XLO) * invW);
    bin = bin < 0 ? 0 : (bin > NBINS - 1 ? NBINS - 1 : bin);
    int pos = atomicAdd(&cur[bin], 1);
    out[pos] = (float4_t){x, y, z, x * x + y * y + z * z};
  }
}

// ---------- pass 2: per-pred outward scan, 4 lanes per pred -------------
__global__ __launch_bounds__(256) void scan_kernel(
    const float4_t* __restrict__ sorted, const int* __restrict__ binBase,
    float* __restrict__ wsmin, int M) {
  int tid = blockIdx.x * 256 + threadIdx.x;
  int p = tid >> 2;   // global pred id over B*2*M
  int sub = tid & 3;  // 0,1 = left lanes; 2,3 = right lanes
  int bs = p / M;
  int pi = p - bs * M;
  const float4_t* src = sorted + (size_t)bs * M;
  const float4_t* ref = sorted + (size_t)(bs ^ 1) * M;
  const int* rbase = binBase + (bs ^ 1) * (NBINS + 1);

  float4_t pp = src[pi];
  float ax = -2.f * pp.x, ay = -2.f * pp.y, az = -2.f * pp.z;
  const float invW = (float)NBINS / (XHI - XLO);
  int bin = (int)((pp.x - XLO) * invW);
  bin = bin < 0 ? 0 : (bin > NBINS - 1 ? NBINS - 1 : bin);
  int pos0 = rbase[bin];

  bool leftside = (sub < 2);
  int step = leftside ? -2 : 2;
  int pos = leftside ? (pos0 - 1 - (sub & 1)) : (pos0 + (sub & 1));
  float mn = 3.0e38f;  // min of (|q|^2 - 2 p.q) over my scanned subset
  bool stopped = false;

  for (int it = 0; it < MAXIT; ++it) {
    if (!stopped) {
#pragma unroll
      for (int k = 0; k < CH; ++k) {  // 8 independent guarded loads
        int pc = pos + step * k;
        if (pc >= 0 && pc < M) {
          float4_t q = ref[pc];
          float d = fmaf(ax, q.x, fmaf(ay, q.y, fmaf(az, q.z, q.w)));
          mn = fminf(mn, d);
        }
      }
      pos += step * CH;
    }
    // exchange best among the 4 lanes of this pred (aligned lane quads)
    float b = fminf(mn, __shfl_xor(mn, 1, 64));
    b = fminf(b, __shfl_xor(b, 2, 64));
    if (!stopped) {
      if (pos < 0 || pos >= M) {
        stopped = true;  // my subsequence exhausted
      } else {
        // x-sorted: |pp.x - ref[pos].x| lower-bounds all my remaining dx
        float dx = pp.x - ref[pos].x;
        // best dist^2 so far = b + |p|^2 (>= 0); 0.05% slack for fp
        if (dx * dx >= (b + pp.w) * 1.0005f) stopped = true;
      }
    }
    if (__all(stopped)) break;
  }

  float b = fminf(mn, __shfl_xor(mn, 1, 64));
  b = fminf(b, __shfl_xor(b, 2, 64));
  if (sub == 0) wsmin[p] = b + pp.w;  // exact NN dist^2 of pred p
}

// ---------- pass 3: sum wsmin -------------------------------------------
__global__ __launch_bounds__(256) void chamfer_reduce_kernel(
    const float* __restrict__ wsmin, float* __restrict__ out, int npts,
    float scale) {
  int tid = blockIdx.x * blockDim.x + threadIdx.x;
  int stride = gridDim.x * blockDim.x;
  double acc = 0.0;
  for (int p = tid; p < npts; p += stride) acc += (double)wsmin[p];
  for (int off = 32; off > 0; off >>= 1) acc += __shfl_down(acc, off, 64);
  __shared__ double wsum[256 / 64];
  int t = threadIdx.x;
  if ((t & 63) == 0) wsum[t >> 6] = acc;
  __syncthreads();
  if (t == 0) {
    double s = 0.0;
#pragma unroll
    for (int w = 0; w < 256 / 64; ++w) s += wsum[w];
    atomicAdd(out, (float)(s * (double)scale));
  }
}

// =================== fallback: R11 brute force (512KB ws) ===============
__global__ __launch_bounds__(THREADS, 2) void chamfer_brute_kernel(
    const float* __restrict__ pred, const float* __restrict__ target,
    float* __restrict__ wsmin, int M) {
  const int blocksPerDir = M / G;  // 64
  int bid = blockIdx.x;
  int pblk = bid % blocksPerDir;
  int rest = bid / blocksPerDir;
  int ts = rest % TSPLIT;
  int bd = rest / TSPLIT;
  int dir = bd & 1;
  int b = bd >> 1;
  const float* src = (dir ? target : pred) + (size_t)b * M * 3;
  const float* ref = (dir ? pred : target) + (size_t)b * M * 3;

  __shared__ float4_t lds[2 * BUFSZ];

  int t = threadIdx.x;
  int g = t >> 4;
  int l = t & 15;

  float ax[P], ay[P], az[P];
  int pbase = pblk * G;
#pragma unroll
  for (int i = 0; i < P; ++i) {
    int p = pbase + l + 16 * i;
    float x = src[p * 3 + 0], y = src[p * 3 + 1], z = src[p * 3 + 2];
    ax[i] = -2.f * x;
    ay[i] = -2.f * y;
    az[i] = -2.f * z;
  }
  float mn[P];
#pragma unroll
  for (int i = 0; i < P; ++i) mn[i] = 3.0e38f;

  const int spanLen = M / TSPLIT;
  const int tbase = ts * spanLen;
  const int sliceLen = spanLen / 32;   // 128
  const int ntiles = sliceLen / TILE;  // 4

  const int sidx = 2 * t;
  const int ss = sidx >> 5;
  const int sjj = sidx & (TILE - 1);
  const int nb = tbase + ss * sliceLen + sjj;
  float rx0, ry0, rz0, rx1, ry1, rz1;

  {
    int n = nb;
    rx0 = ref[n * 3 + 0]; ry0 = ref[n * 3 + 1]; rz0 = ref[n * 3 + 2];
    rx1 = ref[n * 3 + 3]; ry1 = ref[n * 3 + 4]; rz1 = ref[n * 3 + 5];
    float4_t* dst = lds + ss * LSTRIDE + sjj;
    dst[0] = (float4_t){rx0, ry0, rz0, rx0 * rx0 + ry0 * ry0 + rz0 * rz0};
    dst[1] = (float4_t){rx1, ry1, rz1, rx1 * rx1 + ry1 * ry1 + rz1 * rz1};
  }
  __syncthreads();

  int cur = 0;
  for (int k = 0; k < ntiles; ++k) {
    if (k + 1 < ntiles) {
      int n = nb + (k + 1) * TILE;
      rx0 = ref[n * 3 + 0]; ry0 = ref[n * 3 + 1]; rz0 = ref[n * 3 + 2];
      rx1 = ref[n * 3 + 3]; ry1 = ref[n * 3 + 4]; rz1 = ref[n * 3 + 5];
    }
    const float4_t* tp = lds + cur * BUFSZ + g * LSTRIDE;
#pragma unroll 2
    for (int j = 0; j < TILE; j += 4) {
      float4_t q0 = tp[j + 0];
      float4_t q1 = tp[j + 1];
      float4_t q2 = tp[j + 2];
      float4_t q3 = tp[j + 3];
#pragma unroll
      for (int i = 0; i < P; ++i) {
        float d0 = fmaf(ax[i], q0.x, fmaf(ay[i], q0.y, fmaf(az[i], q0.z, q0.w)));
        float d1 = fmaf(ax[i], q1.x, fmaf(ay[i], q1.y, fmaf(az[i], q1.z, q1.w)));
        float d2 = fmaf(ax[i], q2.x, fmaf(ay[i], q2.y, fmaf(az[i], q2.z, q2.w)));
        float d3 = fmaf(ax[i], q3.x, fmaf(ay[i], q3.y, fmaf(az[i], q3.z, q3.w)));
        mn[i] = fminf(fminf(mn[i], d0), d1);
        mn[i] = fminf(fminf(mn[i], d2), d3);
      }
    }
    if (k + 1 < ntiles) {
      float4_t* dst = lds + (cur ^ 1) * BUFSZ + ss * LSTRIDE + sjj;
      dst[0] = (float4_t){rx0, ry0, rz0, rx0 * rx0 + ry0 * ry0 + rz0 * rz0};
      dst[1] = (float4_t){rx1, ry1, rz1, rx1 * rx1 + ry1 * ry1 + rz1 * rz1};
    }
    __syncthreads();
    cur ^= 1;
  }

  float* lmin = (float*)lds;
#pragma unroll
  for (int i = 0; i < P; ++i) lmin[g * G + (l + 16 * i)] = mn[i];
  __syncthreads();
  if (t < G) {
    float m = 3.0e38f;
#pragma unroll
    for (int s = 0; s < 32; ++s) m = fminf(m, lmin[s * G + t]);
    int p = pbase + t;
    float x = src[p * 3 + 0], y = src[p * 3 + 1], z = src[p * 3 + 2];
    int pid = (b * 2 + dir) * M + p;
    wsmin[(size_t)pid * TSPLIT + ts] = (x * x + y * y + z * z) + m;
  }
}

__global__ __launch_bounds__(256) void chamfer_reduce2_kernel(
    const float* __restrict__ wsmin, float* __restrict__ out, int npts,
    float scale) {
  int tid = blockIdx.x * blockDim.x + threadIdx.x;
  int stride = gridDim.x * blockDim.x;
  double acc = 0.0;
  for (int p = tid; p < npts; p += stride) {
    float2_t v = ((const float2_t*)wsmin)[p];
    acc += (double)fminf(v.x, v.y);
  }
  for (int off = 32; off > 0; off >>= 1) acc += __shfl_down(acc, off, 64);
  __shared__ double wsum[256 / 64];
  int t = threadIdx.x;
  if ((t & 63) == 0) wsum[t >> 6] = acc;
  __syncthreads();
  if (t == 0) {
    double s = 0.0;
#pragma unroll
    for (int w = 0; w < 256 / 64; ++w) s += wsum[w];
    atomicAdd(out, (float)(s * (double)scale));
  }
}

extern "C" void kernel_launch(void* const* d_in, const int* in_sizes, int n_in,
                              void* d_out, int out_size, void* d_ws,
                              size_t ws_size, hipStream_t stream) {
  const float* pred = (const float*)d_in[0];
  const float* target = (const float*)d_in[1];
  float* out = (float*)d_out;
  const int B = 4;
  const int M = in_sizes[0] / (B * 3);  // 8192
  float scale = 1.0f / (float)(B * M);

  hipMemsetAsync(out, 0, sizeof(float), stream);  // d_out is poisoned 0xAA

  // layout: wsmin [B*2*M f32] | sorted [B*2*M float4] | binBase
  size_t needWsmin = (size_t)B * 2 * M * 4;           // 256 KB
  size_t needSorted = (size_t)B * 2 * M * 16;         // 1 MB
  size_t needBins = (size_t)B * 2 * (NBINS + 1) * 4;  // ~8 KB
  size_t need = needWsmin + needSorted + needBins;

  if (ws_size >= need) {
    float* wsmin = (float*)d_ws;
    float4_t* sorted = (float4_t*)((char*)d_ws + needWsmin);
    int* binBase = (int*)((char*)sorted + needSorted);

    bin_sort_kernel<<<B * 2, BST, 0, stream>>>(pred, target, sorted, binBase,
                                               M);
    int npreds = B * 2 * M;  // 65536
    scan_kernel<<<npreds * 4 / 256, 256, 0, stream>>>(sorted, binBase, wsmin,
                                                      M);
    chamfer_reduce_kernel<<<64, 256, 0, stream>>>(wsmin, out, npreds, scale);
  } else {
    // fallback: R11 brute force, 512 KB ws (known-good at 46.4us dispatch)
    float* wsmin = (float*)d_ws;
    int blocks = B * 2 * (M / G) * TSPLIT;  // 1024
    chamfer_brute_kernel<<<blocks, THREADS, 0, stream>>>(pred, target, wsmin,
                                                         M);
    int npts = B * 2 * M;
    chamfer_reduce2_kernel<<<64, 256, 0, stream>>>(wsmin, out, npts, scale);
  }
}